// Round 21
// baseline (2155.726 us; speedup 1.0000x reference)
//
#include <hip/hip_runtime.h>
#include <float.h>

// VectorQuantizer: N=262144 rows of D=64 fp32, K=1024 codebook rows.
// out = [x_quantized (N*D f32) | embed_inds (N, written as f32)]
//
// R21 = R20 (f16-dot2 filter + exact fp32 rescore; CORRECT, absmax 0.0)
// with the register spill removed (R20: VGPR capped at 128, +37MB scratch
// FETCH, VALUBusy 27%):
//   - candidate ring 8 -> 4 slots/row (overflow P~7e-4/row -> exact
//     full-scan fallback, still bit-correct)
//   - crow f16 loads split into 2 batches of 4 uint4 (16 live, not 32)
//   - x f16 packs as 32 named scalar uints per row
// Filter margin 1.5e-3 >= 7x worst-case f16-RTZ dot error: every possible
// exact winner reaches the ring; rescore uses the R4-verified bit-exact
// chain with first-min tie-break => output == full exact scan.

typedef __attribute__((address_space(1))) const void gvoid_t;
typedef __attribute__((address_space(3))) void svoid_t;
typedef __fp16 half2_t __attribute__((ext_vector_type(2)));

static constexpr int D_DIM = 64;
static constexpr int K_CB  = 1024;
static constexpr int TPB   = 256;           // 4 waves
static constexpr int RPB   = 512;           // 2 rows/thread -> grid 512
static constexpr int KTILE = 128;           // cb rows per tile
static constexpr int NKT   = K_CB / KTILE;  // 8
static constexpr float MARGIN = 1.5e-3f;

union H2U { unsigned int u; half2_t h; };
__device__ __forceinline__ half2_t h2(unsigned int v) { H2U c; c.u = v; return c.h; }
__device__ __forceinline__ unsigned int u2(half2_t v) { H2U c; c.h = v; return c.u; }

// numpy pairwise-8 sum of squares of 64 values held as 16 float4s.
#define NP_INIT(c0, c1)                                                     \
    float ax = __fmul_rn(c0.x, c0.x), ay = __fmul_rn(c0.y, c0.y),           \
          az = __fmul_rn(c0.z, c0.z), aw = __fmul_rn(c0.w, c0.w);           \
    float bx = __fmul_rn(c1.x, c1.x), by = __fmul_rn(c1.y, c1.y),           \
          bz = __fmul_rn(c1.z, c1.z), bw = __fmul_rn(c1.w, c1.w);
#define NP_ACC(ce, co)                                                      \
    ax = __fadd_rn(ax, __fmul_rn(ce.x, ce.x));                              \
    ay = __fadd_rn(ay, __fmul_rn(ce.y, ce.y));                              \
    az = __fadd_rn(az, __fmul_rn(ce.z, ce.z));                              \
    aw = __fadd_rn(aw, __fmul_rn(ce.w, ce.w));                              \
    bx = __fadd_rn(bx, __fmul_rn(co.x, co.x));                              \
    by = __fadd_rn(by, __fmul_rn(co.y, co.y));                              \
    bz = __fadd_rn(bz, __fmul_rn(co.z, co.z));                              \
    bw = __fadd_rn(bw, __fmul_rn(co.w, co.w));
#define NP_TREE()                                                           \
    __fadd_rn(__fadd_rn(__fadd_rn(ax, ay), __fadd_rn(az, aw)),              \
              __fadd_rn(__fadd_rn(bx, by), __fadd_rn(bz, bw)))

__device__ __forceinline__ float np_pair_sq16(
        float4 c0, float4 c1, float4 c2, float4 c3,
        float4 c4, float4 c5, float4 c6, float4 c7,
        float4 c8, float4 c9, float4 c10, float4 c11,
        float4 c12, float4 c13, float4 c14, float4 c15) {
    NP_INIT(c0, c1)
    NP_ACC(c2, c3)  NP_ACC(c4, c5)  NP_ACC(c6, c7)
    NP_ACC(c8, c9)  NP_ACC(c10, c11) NP_ACC(c12, c13) NP_ACC(c14, c15)
    return NP_TREE();
}

// Exact score: R4-verified bit-exact chain.
__device__ __forceinline__ float exact_sc(const float* xp, const float* cb,
                                          int k, float xn, float en) {
    const float4* xr = reinterpret_cast<const float4*>(xp);
    const float4* cr = reinterpret_cast<const float4*>(cb + (size_t)k * D_DIM);
    float d = 0.f;
#pragma unroll
    for (int c = 0; c < 16; ++c) {
        const float4 xv = xr[c], q = cr[c];
        d = __fmaf_rn(q.x, xv.x, d);
        d = __fmaf_rn(q.y, xv.y, d);
        d = __fmaf_rn(q.z, xv.z, d);
        d = __fmaf_rn(q.w, xv.w, d);
    }
    return __fmaf_rn(-2.f, d, __fadd_rn(xn, en));
}

__device__ __forceinline__ uint4 pkrow(float4 a, float4 b) {
    uint4 r;
    r.x = u2(__builtin_amdgcn_cvt_pkrtz(a.x, a.y));
    r.y = u2(__builtin_amdgcn_cvt_pkrtz(a.z, a.w));
    r.z = u2(__builtin_amdgcn_cvt_pkrtz(b.x, b.y));
    r.w = u2(__builtin_amdgcn_cvt_pkrtz(b.z, b.w));
    return r;
}

// Pack 8 dims (2 float4s) into 4 named scalar uints of row p.
#define PK4(p, i0, i1, i2, i3, va, vb)                                      \
    { const uint4 t_ = pkrow(va, vb);                                       \
      p##i0 = t_.x; p##i1 = t_.y; p##i2 = t_.z; p##i3 = t_.w; }

// 4 uint-pairs (8 dims) for both rows from one uint4 of cb-f16.
#define FD4(qv, i0, i1, i2, i3)                                             \
    dA = __builtin_amdgcn_fdot2(h2(qv.x), h2(ua##i0), dA, false);           \
    dB = __builtin_amdgcn_fdot2(h2(qv.x), h2(ub##i0), dB, false);           \
    dA = __builtin_amdgcn_fdot2(h2(qv.y), h2(ua##i1), dA, false);           \
    dB = __builtin_amdgcn_fdot2(h2(qv.y), h2(ub##i1), dB, false);           \
    dA = __builtin_amdgcn_fdot2(h2(qv.z), h2(ua##i2), dA, false);           \
    dB = __builtin_amdgcn_fdot2(h2(qv.z), h2(ub##i2), dB, false);           \
    dA = __builtin_amdgcn_fdot2(h2(qv.w), h2(ua##i3), dA, false);           \
    dB = __builtin_amdgcn_fdot2(h2(qv.w), h2(ub##i3), dB, false);

#define RING_DECL(R)                                                        \
    int   rk##R##0 = 0, rk##R##1 = 0, rk##R##2 = 0, rk##R##3 = 0;           \
    float rt##R##0 = FLT_MAX, rt##R##1 = FLT_MAX,                           \
          rt##R##2 = FLT_MAX, rt##R##3 = FLT_MAX;

#define PSLOT(R, i)                                                         \
    { const bool st_ = (rt##R##i >= th_) && !pl_;                           \
      rk##R##i = st_ ? k : rk##R##i;                                        \
      rt##R##i = st_ ? tv_ : rt##R##i;                                      \
      pl_ = pl_ || st_; }

#define PUSH(R, tv)                                                         \
    if ((tv) < rm##R + MARGIN) {                                            \
        rm##R = fminf(rm##R, (tv));                                         \
        const float th_ = rm##R + MARGIN;                                   \
        const float tv_ = (tv);                                             \
        bool pl_ = false;                                                   \
        PSLOT(R,0) PSLOT(R,1) PSLOT(R,2) PSLOT(R,3)                         \
        ovf##R = ovf##R || !pl_;                                            \
    }

#define RES(R, i)                                                           \
    if (rt##R##i < FLT_MAX) {                                               \
        const int kc_ = rk##R##i;                                           \
        const float s_ = exact_sc(xp##R, cb, kc_, xn##R, es[kc_]);          \
        if (s_ < bs##R || (s_ == bs##R && kc_ < bk##R)) { bs##R = s_; bk##R = kc_; } }

__global__ void __launch_bounds__(TPB)
__attribute__((amdgpu_waves_per_eu(2, 2)))
vq_kernel(
        const float* __restrict__ x, const float* __restrict__ cb,
        float* __restrict__ out_q, float* __restrict__ out_idx) {
    __shared__ unsigned long long cbt16[2][KTILE * D_DIM / 4]; // 2x16KB f16 tiles
    __shared__ float fstage[KTILE * D_DIM];                    // 32KB fp32 stage
    __shared__ float es[K_CB];                                 // 4KB
    __shared__ int   bks[RPB];                                 // 2KB  (~70KB)

    const int tid = threadIdx.x;
    const size_t row0 = (size_t)blockIdx.x * RPB;
    const size_t rowA = row0 + tid;
    const size_t rowB = row0 + TPB + tid;
    const float4* cb4 = reinterpret_cast<const float4*>(cb);

    // ---- prologue: async-stage fp32 tile 0 ----
#pragma unroll
    for (int j = 0; j < 8; ++j) {
        const int f = tid + TPB * j;
        __builtin_amdgcn_global_load_lds(
            (gvoid_t*)(cb + (size_t)f * 4),
            (svoid_t*)(&fstage[f * 4]), 16, 0, 0);
    }

    // ---- phase A: e-norms (numpy pairwise order, R4-verified) ----
#pragma unroll
    for (int j = 0; j < K_CB / TPB; ++j) {
        const int k = tid + TPB * j;
        const float4* cr = cb4 + (size_t)k * 16;
        float4 c0 = cr[0],  c1 = cr[1],  c2 = cr[2],  c3 = cr[3],
               c4 = cr[4],  c5 = cr[5],  c6 = cr[6],  c7 = cr[7],
               c8 = cr[8],  c9 = cr[9],  c10 = cr[10], c11 = cr[11],
               c12 = cr[12], c13 = cr[13], c14 = cr[14], c15 = cr[15];
        es[k] = np_pair_sq16(c0, c1, c2, c3, c4, c5, c6, c7,
                             c8, c9, c10, c11, c12, c13, c14, c15);
    }

    // ---- phase B: x rows -> xn (fp32, numpy) + 32 named uint f16 packs ----
    unsigned ua0, ua1, ua2, ua3, ua4, ua5, ua6, ua7,
             ua8, ua9, ua10, ua11, ua12, ua13, ua14, ua15,
             ua16, ua17, ua18, ua19, ua20, ua21, ua22, ua23,
             ua24, ua25, ua26, ua27, ua28, ua29, ua30, ua31;
    unsigned ub0, ub1, ub2, ub3, ub4, ub5, ub6, ub7,
             ub8, ub9, ub10, ub11, ub12, ub13, ub14, ub15,
             ub16, ub17, ub18, ub19, ub20, ub21, ub22, ub23,
             ub24, ub25, ub26, ub27, ub28, ub29, ub30, ub31;

    const float4* ga = reinterpret_cast<const float4*>(x + rowA * D_DIM);
    float4 v0 = ga[0],  v1 = ga[1],  v2 = ga[2],  v3 = ga[3],
           v4 = ga[4],  v5 = ga[5],  v6 = ga[6],  v7 = ga[7],
           v8 = ga[8],  v9 = ga[9],  v10 = ga[10], v11 = ga[11],
           v12 = ga[12], v13 = ga[13], v14 = ga[14], v15 = ga[15];
    const float xnA = np_pair_sq16(v0, v1, v2, v3, v4, v5, v6, v7,
                                   v8, v9, v10, v11, v12, v13, v14, v15);
    PK4(ua, 0, 1, 2, 3,     v0,  v1)   PK4(ua, 4, 5, 6, 7,     v2,  v3)
    PK4(ua, 8, 9, 10, 11,   v4,  v5)   PK4(ua, 12, 13, 14, 15, v6,  v7)
    PK4(ua, 16, 17, 18, 19, v8,  v9)   PK4(ua, 20, 21, 22, 23, v10, v11)
    PK4(ua, 24, 25, 26, 27, v12, v13)  PK4(ua, 28, 29, 30, 31, v14, v15)

    const float4* gb = reinterpret_cast<const float4*>(x + rowB * D_DIM);
    v0 = gb[0];  v1 = gb[1];  v2 = gb[2];  v3 = gb[3];
    v4 = gb[4];  v5 = gb[5];  v6 = gb[6];  v7 = gb[7];
    v8 = gb[8];  v9 = gb[9];  v10 = gb[10]; v11 = gb[11];
    v12 = gb[12]; v13 = gb[13]; v14 = gb[14]; v15 = gb[15];
    const float xnB = np_pair_sq16(v0, v1, v2, v3, v4, v5, v6, v7,
                                   v8, v9, v10, v11, v12, v13, v14, v15);
    PK4(ub, 0, 1, 2, 3,     v0,  v1)   PK4(ub, 4, 5, 6, 7,     v2,  v3)
    PK4(ub, 8, 9, 10, 11,   v4,  v5)   PK4(ub, 12, 13, 14, 15, v6,  v7)
    PK4(ub, 16, 17, 18, 19, v8,  v9)   PK4(ub, 20, 21, 22, 23, v10, v11)
    PK4(ub, 24, 25, 26, 27, v12, v13)  PK4(ub, 28, 29, 30, 31, v14, v15)

    // tile 0: wait, convert fp32->f16, then stage tile 1
    asm volatile("s_waitcnt vmcnt(0)" ::: "memory");
    __syncthreads();
#pragma unroll
    for (int j = 0; j < 8; ++j) {
        const int f = tid + TPB * j;
        const float4 v = reinterpret_cast<const float4*>(fstage)[f];
        const unsigned long long w =
            ((unsigned long long)u2(__builtin_amdgcn_cvt_pkrtz(v.z, v.w)) << 32)
            | u2(__builtin_amdgcn_cvt_pkrtz(v.x, v.y));
        cbt16[0][f] = w;
    }
    __syncthreads();
#pragma unroll
    for (int j = 0; j < 8; ++j) {
        const int f = tid + TPB * j;
        __builtin_amdgcn_global_load_lds(
            (gvoid_t*)(cb + (size_t)KTILE * D_DIM + (size_t)f * 4),
            (svoid_t*)(&fstage[f * 4]), 16, 0, 0);
    }

    // ---- phase C: filter scan with 4-slot candidate rings ----
    float rmA = FLT_MAX, rmB = FLT_MAX;
    bool ovfA = false, ovfB = false;
    RING_DECL(A) RING_DECL(B)

    for (int t = 0; t < NKT; ++t) {
        const uint4* tp = reinterpret_cast<const uint4*>(cbt16[t & 1]);
#pragma unroll 2
        for (int kk = 0; kk < KTILE; ++kk) {
            const int k = t * KTILE + kk;
            const uint4* crow = tp + kk * 8;
            const float en = es[k];
            float dA = 0.f, dB = 0.f;
            {   // dims 0..31
                const uint4 q0 = crow[0], q1 = crow[1], q2 = crow[2], q3 = crow[3];
                FD4(q0, 0, 1, 2, 3)     FD4(q1, 4, 5, 6, 7)
                FD4(q2, 8, 9, 10, 11)   FD4(q3, 12, 13, 14, 15)
            }
            {   // dims 32..63
                const uint4 q4 = crow[4], q5 = crow[5], q6 = crow[6], q7 = crow[7];
                FD4(q4, 16, 17, 18, 19) FD4(q5, 20, 21, 22, 23)
                FD4(q6, 24, 25, 26, 27) FD4(q7, 28, 29, 30, 31)
            }
            const float tA = __fmaf_rn(-2.f, dA, en);
            const float tB = __fmaf_rn(-2.f, dB, en);
            PUSH(A, tA)
            PUSH(B, tB)
        }
        if (t + 1 < NKT) {
            asm volatile("s_waitcnt vmcnt(0)" ::: "memory"); // fp32 t+1 landed
            __syncthreads();                                 // compute(t) done
#pragma unroll
            for (int j = 0; j < 8; ++j) {                    // convert -> f16 buf
                const int f = tid + TPB * j;
                const float4 v = reinterpret_cast<const float4*>(fstage)[f];
                const unsigned long long w =
                    ((unsigned long long)u2(__builtin_amdgcn_cvt_pkrtz(v.z, v.w)) << 32)
                    | u2(__builtin_amdgcn_cvt_pkrtz(v.x, v.y));
                cbt16[(t + 1) & 1][f] = w;
            }
            __syncthreads();                                 // fstage free
            if (t + 2 < NKT) {
#pragma unroll
                for (int j = 0; j < 8; ++j) {
                    const int f = tid + TPB * j;
                    __builtin_amdgcn_global_load_lds(
                        (gvoid_t*)(cb + (size_t)(t + 2) * KTILE * D_DIM + (size_t)f * 4),
                        (svoid_t*)(&fstage[f * 4]), 16, 0, 0);
                }
            }
        }
    }

    // ---- exact rescore of candidates (bit-exact chain, first-min) ----
    const float* xpA = x + rowA * D_DIM;
    const float* xpB = x + rowB * D_DIM;
    float bsA = FLT_MAX, bsB = FLT_MAX;
    int bkA = 0, bkB = 0;
    if (ovfA) {
#pragma unroll 1
        for (int k = 0; k < K_CB; ++k) {
            const float s = exact_sc(xpA, cb, k, xnA, es[k]);
            if (s < bsA) { bsA = s; bkA = k; }
        }
    } else {
        RES(A, 0) RES(A, 1) RES(A, 2) RES(A, 3)
    }
    if (ovfB) {
#pragma unroll 1
        for (int k = 0; k < K_CB; ++k) {
            const float s = exact_sc(xpB, cb, k, xnB, es[k]);
            if (s < bsB) { bsB = s; bkB = k; }
        }
    } else {
        RES(B, 0) RES(B, 1) RES(B, 2) RES(B, 3)
    }

    bks[tid]       = bkA;
    bks[TPB + tid] = bkB;
    out_idx[rowA] = (float)bkA;
    out_idx[rowB] = (float)bkB;
    __syncthreads();

    // ---- phase D: coalesced gather-write of x_quantized ----
    float4* oq = reinterpret_cast<float4*>(out_q + row0 * D_DIM);
#pragma unroll
    for (int j = 0; j < RPB * 16 / TPB; ++j) {
        const int f = tid + TPB * j;
        const int r = f >> 4, c = f & 15;
        oq[f] = cb4[(size_t)bks[r] * 16 + c];
    }
}

extern "C" void kernel_launch(void* const* d_in, const int* in_sizes, int n_in,
                              void* d_out, int out_size, void* d_ws, size_t ws_size,
                              hipStream_t stream) {
    const float* x  = (const float*)d_in[0];
    const float* cb = (const float*)d_in[1];
    const int n_rows = in_sizes[0] / D_DIM;     // 262144

    float* out_q   = (float*)d_out;
    float* out_idx = out_q + (size_t)n_rows * D_DIM;

    vq_kernel<<<n_rows / RPB, TPB, 0, stream>>>(x, cb, out_q, out_idx);
}

// Round 23
// 1526.629 us; speedup vs baseline: 1.4121x; 1.4121x over previous
//
#include <hip/hip_runtime.h>
#include <float.h>

// VectorQuantizer: N=262144 rows of D=64 fp32, K=1024 codebook rows.
// out = [x_quantized (N*D f32) | embed_inds (N, written as f32)]
//
// R23 = R21 (hardware-validated f16-dot2 filter + exact fp32 rescore,
// absmax 0.0) reduced to 1 ROW/THREAD, nothing else changed:
//   - R22's failure was a RACY es[K_CB-1]+=0 "keepalive" (cross-wave RMW of
//     uninitialized LDS before any barrier -> whole-block index corruption).
//     Removed. xn is a plain local again. No other novel constructs.
//   - Register budget: 32 x-f16 packs + 16 ring(8 slots) + 16 crow + ~23
//     misc = ~87 < 128 cap -> no spill (R20/R21 spilled at 2 rows/thread).
//   - Filter: v_dot2_f32_f16, two accumulator chains (filter-only rounding;
//     margin 1.5e-3 >> worst-case f16-RTZ dot error, Hoeffding e^-45).
//   - Rescore: R4-verified bit-exact chain, first-min tie-break.
//   - Ring overflow (P~1e-8/row): deterministic exact full-scan fallback.

typedef __attribute__((address_space(1))) const void gvoid_t;
typedef __attribute__((address_space(3))) void svoid_t;
typedef __fp16 half2_t __attribute__((ext_vector_type(2)));

static constexpr int D_DIM = 64;
static constexpr int K_CB  = 1024;
static constexpr int TPB   = 256;           // 4 waves; 1 row/thread
static constexpr int KTILE = 128;           // cb rows per tile
static constexpr int NKT   = K_CB / KTILE;  // 8
static constexpr float MARGIN = 1.5e-3f;

union H2U { unsigned int u; half2_t h; };
__device__ __forceinline__ half2_t h2(unsigned int v) { H2U c; c.u = v; return c.h; }
__device__ __forceinline__ unsigned int u2(half2_t v) { H2U c; c.h = v; return c.u; }

// numpy pairwise-8 sum of squares of 64 values held as 16 float4s.
#define NP_INIT(c0, c1)                                                     \
    float ax = __fmul_rn(c0.x, c0.x), ay = __fmul_rn(c0.y, c0.y),           \
          az = __fmul_rn(c0.z, c0.z), aw = __fmul_rn(c0.w, c0.w);           \
    float bx = __fmul_rn(c1.x, c1.x), by = __fmul_rn(c1.y, c1.y),           \
          bz = __fmul_rn(c1.z, c1.z), bw = __fmul_rn(c1.w, c1.w);
#define NP_ACC(ce, co)                                                      \
    ax = __fadd_rn(ax, __fmul_rn(ce.x, ce.x));                              \
    ay = __fadd_rn(ay, __fmul_rn(ce.y, ce.y));                              \
    az = __fadd_rn(az, __fmul_rn(ce.z, ce.z));                              \
    aw = __fadd_rn(aw, __fmul_rn(ce.w, ce.w));                              \
    bx = __fadd_rn(bx, __fmul_rn(co.x, co.x));                              \
    by = __fadd_rn(by, __fmul_rn(co.y, co.y));                              \
    bz = __fadd_rn(bz, __fmul_rn(co.z, co.z));                              \
    bw = __fadd_rn(bw, __fmul_rn(co.w, co.w));
#define NP_TREE()                                                           \
    __fadd_rn(__fadd_rn(__fadd_rn(ax, ay), __fadd_rn(az, aw)),              \
              __fadd_rn(__fadd_rn(bx, by), __fadd_rn(bz, bw)))

__device__ __forceinline__ float np_pair_sq16(
        float4 c0, float4 c1, float4 c2, float4 c3,
        float4 c4, float4 c5, float4 c6, float4 c7,
        float4 c8, float4 c9, float4 c10, float4 c11,
        float4 c12, float4 c13, float4 c14, float4 c15) {
    NP_INIT(c0, c1)
    NP_ACC(c2, c3)  NP_ACC(c4, c5)  NP_ACC(c6, c7)
    NP_ACC(c8, c9)  NP_ACC(c10, c11) NP_ACC(c12, c13) NP_ACC(c14, c15)
    return NP_TREE();
}

// Exact score: R4-verified bit-exact chain.
__device__ __forceinline__ float exact_sc(const float* xp, const float* cb,
                                          int k, float xn, float en) {
    const float4* xr = reinterpret_cast<const float4*>(xp);
    const float4* cr = reinterpret_cast<const float4*>(cb + (size_t)k * D_DIM);
    float d = 0.f;
#pragma unroll
    for (int c = 0; c < 16; ++c) {
        const float4 xv = xr[c], q = cr[c];
        d = __fmaf_rn(q.x, xv.x, d);
        d = __fmaf_rn(q.y, xv.y, d);
        d = __fmaf_rn(q.z, xv.z, d);
        d = __fmaf_rn(q.w, xv.w, d);
    }
    return __fmaf_rn(-2.f, d, __fadd_rn(xn, en));
}

__device__ __forceinline__ uint4 pkrow(float4 a, float4 b) {
    uint4 r;
    r.x = u2(__builtin_amdgcn_cvt_pkrtz(a.x, a.y));
    r.y = u2(__builtin_amdgcn_cvt_pkrtz(a.z, a.w));
    r.z = u2(__builtin_amdgcn_cvt_pkrtz(b.x, b.y));
    r.w = u2(__builtin_amdgcn_cvt_pkrtz(b.z, b.w));
    return r;
}

#define PK4(p, i0, i1, i2, i3, va, vb)                                      \
    { const uint4 t_ = pkrow(va, vb);                                       \
      p##i0 = t_.x; p##i1 = t_.y; p##i2 = t_.z; p##i3 = t_.w; }

// 4 uint-pairs (8 dims) into chain acc from one uint4 of cb-f16.
#define FD4(acc, qv, i0, i1, i2, i3)                                        \
    acc = __builtin_amdgcn_fdot2(h2(qv.x), h2(ua##i0), acc, false);         \
    acc = __builtin_amdgcn_fdot2(h2(qv.y), h2(ua##i1), acc, false);         \
    acc = __builtin_amdgcn_fdot2(h2(qv.z), h2(ua##i2), acc, false);         \
    acc = __builtin_amdgcn_fdot2(h2(qv.w), h2(ua##i3), acc, false);

#define PSLOT(i)                                                            \
    { const bool st_ = (rt##i >= th_) && !pl_;                              \
      rk##i = st_ ? k : rk##i;                                              \
      rt##i = st_ ? tv_ : rt##i;                                            \
      pl_ = pl_ || st_; }

#define RES(i)                                                              \
    if (rt##i < FLT_MAX) {                                                  \
        const int kc_ = rk##i;                                              \
        const float s_ = exact_sc(xp, cb, kc_, xn, es[kc_]);                \
        if (s_ < bs || (s_ == bs && kc_ < bk)) { bs = s_; bk = kc_; } }

__global__ void __launch_bounds__(TPB)
__attribute__((amdgpu_waves_per_eu(2, 2)))
vq_kernel(
        const float* __restrict__ x, const float* __restrict__ cb,
        float* __restrict__ out_q, float* __restrict__ out_idx) {
    __shared__ unsigned long long cbt16[2][KTILE * D_DIM / 4]; // 2x16KB f16 tiles
    __shared__ float fstage[KTILE * D_DIM];                    // 32KB fp32 stage
    __shared__ float es[K_CB];                                 // 4KB
    __shared__ int   bks[TPB];                                 // 1KB  (~69.6KB)

    const int tid = threadIdx.x;
    const size_t row0 = (size_t)blockIdx.x * TPB;
    const size_t row  = row0 + tid;
    const float4* cb4 = reinterpret_cast<const float4*>(cb);

    // ---- prologue: async-stage fp32 tile 0 ----
#pragma unroll
    for (int j = 0; j < 8; ++j) {
        const int f = tid + TPB * j;
        __builtin_amdgcn_global_load_lds(
            (gvoid_t*)(cb + (size_t)f * 4),
            (svoid_t*)(&fstage[f * 4]), 16, 0, 0);
    }

    // ---- phase A: e-norms (numpy pairwise order, R4-verified) ----
#pragma unroll
    for (int j = 0; j < K_CB / TPB; ++j) {
        const int k = tid + TPB * j;
        const float4* cr = cb4 + (size_t)k * 16;
        float4 c0 = cr[0],  c1 = cr[1],  c2 = cr[2],  c3 = cr[3],
               c4 = cr[4],  c5 = cr[5],  c6 = cr[6],  c7 = cr[7],
               c8 = cr[8],  c9 = cr[9],  c10 = cr[10], c11 = cr[11],
               c12 = cr[12], c13 = cr[13], c14 = cr[14], c15 = cr[15];
        es[k] = np_pair_sq16(c0, c1, c2, c3, c4, c5, c6, c7,
                             c8, c9, c10, c11, c12, c13, c14, c15);
    }

    // ---- phase B: my row -> xn (fp32, numpy) + 32 named uint f16 packs ----
    unsigned ua0, ua1, ua2, ua3, ua4, ua5, ua6, ua7,
             ua8, ua9, ua10, ua11, ua12, ua13, ua14, ua15,
             ua16, ua17, ua18, ua19, ua20, ua21, ua22, ua23,
             ua24, ua25, ua26, ua27, ua28, ua29, ua30, ua31;
    float xn;
    {
        const float4* ga = reinterpret_cast<const float4*>(x + row * D_DIM);
        float4 v0 = ga[0],  v1 = ga[1],  v2 = ga[2],  v3 = ga[3],
               v4 = ga[4],  v5 = ga[5],  v6 = ga[6],  v7 = ga[7],
               v8 = ga[8],  v9 = ga[9],  v10 = ga[10], v11 = ga[11],
               v12 = ga[12], v13 = ga[13], v14 = ga[14], v15 = ga[15];
        xn = np_pair_sq16(v0, v1, v2, v3, v4, v5, v6, v7,
                          v8, v9, v10, v11, v12, v13, v14, v15);
        PK4(ua, 0, 1, 2, 3,     v0,  v1)   PK4(ua, 4, 5, 6, 7,     v2,  v3)
        PK4(ua, 8, 9, 10, 11,   v4,  v5)   PK4(ua, 12, 13, 14, 15, v6,  v7)
        PK4(ua, 16, 17, 18, 19, v8,  v9)   PK4(ua, 20, 21, 22, 23, v10, v11)
        PK4(ua, 24, 25, 26, 27, v12, v13)  PK4(ua, 28, 29, 30, 31, v14, v15)
    }

    // tile 0: wait, convert fp32->f16, then stage tile 1
    asm volatile("s_waitcnt vmcnt(0)" ::: "memory");
    __syncthreads();
#pragma unroll
    for (int j = 0; j < 8; ++j) {
        const int f = tid + TPB * j;
        const float4 v = reinterpret_cast<const float4*>(fstage)[f];
        const unsigned long long w =
            ((unsigned long long)u2(__builtin_amdgcn_cvt_pkrtz(v.z, v.w)) << 32)
            | u2(__builtin_amdgcn_cvt_pkrtz(v.x, v.y));
        cbt16[0][f] = w;
    }
    __syncthreads();
#pragma unroll
    for (int j = 0; j < 8; ++j) {
        const int f = tid + TPB * j;
        __builtin_amdgcn_global_load_lds(
            (gvoid_t*)(cb + (size_t)KTILE * D_DIM + (size_t)f * 4),
            (svoid_t*)(&fstage[f * 4]), 16, 0, 0);
    }

    // ---- phase C: filter scan, 8-slot candidate ring, 2 dot chains ----
    float rm = FLT_MAX;
    bool ovf = false;
    int   rk0 = 0, rk1 = 0, rk2 = 0, rk3 = 0, rk4 = 0, rk5 = 0, rk6 = 0, rk7 = 0;
    float rt0 = FLT_MAX, rt1 = FLT_MAX, rt2 = FLT_MAX, rt3 = FLT_MAX,
          rt4 = FLT_MAX, rt5 = FLT_MAX, rt6 = FLT_MAX, rt7 = FLT_MAX;

    for (int t = 0; t < NKT; ++t) {
        const uint4* tp = reinterpret_cast<const uint4*>(cbt16[t & 1]);
#pragma unroll 2
        for (int kk = 0; kk < KTILE; ++kk) {
            const int k = t * KTILE + kk;
            const uint4* crow = tp + kk * 8;
            const float en = es[k];
            float d0 = 0.f, d1 = 0.f;          // two chains for ILP
            {   // dims 0..31 -> chain 0
                const uint4 q0 = crow[0], q1 = crow[1], q2 = crow[2], q3 = crow[3];
                FD4(d0, q0, 0, 1, 2, 3)     FD4(d0, q1, 4, 5, 6, 7)
                FD4(d0, q2, 8, 9, 10, 11)   FD4(d0, q3, 12, 13, 14, 15)
            }
            {   // dims 32..63 -> chain 1
                const uint4 q4 = crow[4], q5 = crow[5], q6 = crow[6], q7 = crow[7];
                FD4(d1, q4, 16, 17, 18, 19) FD4(d1, q5, 20, 21, 22, 23)
                FD4(d1, q6, 24, 25, 26, 27) FD4(d1, q7, 28, 29, 30, 31)
            }
            const float tA = __fmaf_rn(-2.f, __fadd_rn(d0, d1), en);
            if (tA < rm + MARGIN) {
                rm = fminf(rm, tA);
                const float th_ = rm + MARGIN;
                const float tv_ = tA;
                bool pl_ = false;
                PSLOT(0) PSLOT(1) PSLOT(2) PSLOT(3)
                PSLOT(4) PSLOT(5) PSLOT(6) PSLOT(7)
                ovf = ovf || !pl_;
            }
        }
        if (t + 1 < NKT) {
            asm volatile("s_waitcnt vmcnt(0)" ::: "memory"); // fp32 t+1 landed
            __syncthreads();                                 // compute(t) done
#pragma unroll
            for (int j = 0; j < 8; ++j) {                    // convert -> f16 buf
                const int f = tid + TPB * j;
                const float4 v = reinterpret_cast<const float4*>(fstage)[f];
                const unsigned long long w =
                    ((unsigned long long)u2(__builtin_amdgcn_cvt_pkrtz(v.z, v.w)) << 32)
                    | u2(__builtin_amdgcn_cvt_pkrtz(v.x, v.y));
                cbt16[(t + 1) & 1][f] = w;
            }
            __syncthreads();                                 // fstage free
            if (t + 2 < NKT) {
#pragma unroll
                for (int j = 0; j < 8; ++j) {
                    const int f = tid + TPB * j;
                    __builtin_amdgcn_global_load_lds(
                        (gvoid_t*)(cb + (size_t)(t + 2) * KTILE * D_DIM + (size_t)f * 4),
                        (svoid_t*)(&fstage[f * 4]), 16, 0, 0);
                }
            }
        }
    }

    // ---- exact rescore (bit-exact chain, first-min) ----
    const float* xp = x + row * D_DIM;
    float bs = FLT_MAX;
    int bk = 0;
    if (ovf) {
#pragma unroll 1
        for (int k = 0; k < K_CB; ++k) {
            const float s = exact_sc(xp, cb, k, xn, es[k]);
            if (s < bs) { bs = s; bk = k; }
        }
    } else {
        RES(0) RES(1) RES(2) RES(3) RES(4) RES(5) RES(6) RES(7)
    }

    bks[tid] = bk;
    out_idx[row] = (float)bk;
    __syncthreads();

    // ---- phase D: coalesced gather-write of x_quantized ----
    float4* oq = reinterpret_cast<float4*>(out_q + row0 * D_DIM);
#pragma unroll
    for (int j = 0; j < 16; ++j) {
        const int f = tid + TPB * j;     // 0..4095
        const int r = f >> 4, c = f & 15;
        oq[f] = cb4[(size_t)bks[r] * 16 + c];
    }
}

extern "C" void kernel_launch(void* const* d_in, const int* in_sizes, int n_in,
                              void* d_out, int out_size, void* d_ws, size_t ws_size,
                              hipStream_t stream) {
    const float* x  = (const float*)d_in[0];
    const float* cb = (const float*)d_in[1];
    const int n_rows = in_sizes[0] / D_DIM;     // 262144

    float* out_q   = (float*)d_out;
    float* out_idx = out_q + (size_t)n_rows * D_DIM;

    vq_kernel<<<n_rows / TPB, TPB, 0, stream>>>(x, cb, out_q, out_idx);
}

// Round 24
// 1226.202 us; speedup vs baseline: 1.7581x; 1.2450x over previous
//
#include <hip/hip_runtime.h>
#include <float.h>

// VectorQuantizer: N=262144 rows of D=64 fp32, K=1024 codebook rows.
// out = [x_quantized (N*D f32) | embed_inds (N, written as f32)]
//
// R24: bf16 MFMA filter + exact fp32 rescore.
//   - R23 proved the fdot2 path is emulated on gfx950 (~3x VALU inflation);
//     fp32-VALU family capped ~450us (218us FMA floor + LDS delivery).
//   - Filter: mfma_f32_16x16x32_bf16; per wave-tile 16rows x 16k x 64d via
//     2 chained MFMA. Pass1: per-row min (shfl_xor reduce). Pass2: identical
//     sweep pushes all (row,k) with t < min+MARGIN into per-row LDS slots.
//   - MARGIN 3e-3 >= 2x deterministic worst-case bf16-RNE score error
//     (err <= 2*Sum|x_i c_i|*2^-8 <= 1.4e-3) -> exact winner provably in set.
//   - Rescore: R4-verified bit-exact chain (seq fmaf dot, numpy norms,
//     fmaf(-2,d,fadd(xn,es))), first-min tie-break. cnt>8 -> exact full scan.
//   - LDS bf16 tiles XOR-swizzled: byte ^= (row&7)<<4, same macro both sides.

typedef __attribute__((ext_vector_type(8))) short short8;
typedef __attribute__((ext_vector_type(4))) float f32x4;

static constexpr int D_DIM = 64;
static constexpr int K_CB  = 1024;
static constexpr int TPB   = 256;          // 4 waves; 1 row/thread for scalar phases
static constexpr int BM    = 256;          // x rows per block
static constexpr int KTR   = 256;          // cb rows per staged bf16 tile
static constexpr int NKT   = K_CB / KTR;   // 4
static constexpr float MARGIN = 3e-3f;

// bf16 RNE pack of two f32 -> uint (lo = bf16(a), hi = bf16(b))
__device__ __forceinline__ unsigned bf2(float a, float b) {
    unsigned ua = __float_as_uint(a), ub = __float_as_uint(b);
    ua += 0x7FFFu + ((ua >> 16) & 1u);
    ub += 0x7FFFu + ((ub >> 16) & 1u);
    return (ua >> 16) | (ub & 0xFFFF0000u);
}

// numpy pairwise-8 sum of squares of 64 values held as 16 float4s.
#define NP_INIT(c0, c1)                                                     \
    float ax = __fmul_rn(c0.x, c0.x), ay = __fmul_rn(c0.y, c0.y),           \
          az = __fmul_rn(c0.z, c0.z), aw = __fmul_rn(c0.w, c0.w);           \
    float bx = __fmul_rn(c1.x, c1.x), by = __fmul_rn(c1.y, c1.y),           \
          bz = __fmul_rn(c1.z, c1.z), bw = __fmul_rn(c1.w, c1.w);
#define NP_ACC(ce, co)                                                      \
    ax = __fadd_rn(ax, __fmul_rn(ce.x, ce.x));                              \
    ay = __fadd_rn(ay, __fmul_rn(ce.y, ce.y));                              \
    az = __fadd_rn(az, __fmul_rn(ce.z, ce.z));                              \
    aw = __fadd_rn(aw, __fmul_rn(ce.w, ce.w));                              \
    bx = __fadd_rn(bx, __fmul_rn(co.x, co.x));                              \
    by = __fadd_rn(by, __fmul_rn(co.y, co.y));                              \
    bz = __fadd_rn(bz, __fmul_rn(co.z, co.z));                              \
    bw = __fadd_rn(bw, __fmul_rn(co.w, co.w));
#define NP_TREE()                                                           \
    __fadd_rn(__fadd_rn(__fadd_rn(ax, ay), __fadd_rn(az, aw)),              \
              __fadd_rn(__fadd_rn(bx, by), __fadd_rn(bz, bw)))

__device__ __forceinline__ float np_pair_sq16(
        float4 c0, float4 c1, float4 c2, float4 c3,
        float4 c4, float4 c5, float4 c6, float4 c7,
        float4 c8, float4 c9, float4 c10, float4 c11,
        float4 c12, float4 c13, float4 c14, float4 c15) {
    NP_INIT(c0, c1)
    NP_ACC(c2, c3)  NP_ACC(c4, c5)  NP_ACC(c6, c7)
    NP_ACC(c8, c9)  NP_ACC(c10, c11) NP_ACC(c12, c13) NP_ACC(c14, c15)
    return NP_TREE();
}

// Exact score: R4-verified bit-exact chain.
__device__ __forceinline__ float exact_sc(const float* xp, const float* cb,
                                          int k, float xn, float en) {
    const float4* xr = reinterpret_cast<const float4*>(xp);
    const float4* cr = reinterpret_cast<const float4*>(cb + (size_t)k * D_DIM);
    float d = 0.f;
#pragma unroll
    for (int c = 0; c < 16; ++c) {
        const float4 xv = xr[c], q = cr[c];
        d = __fmaf_rn(q.x, xv.x, d);
        d = __fmaf_rn(q.y, xv.y, d);
        d = __fmaf_rn(q.z, xv.z, d);
        d = __fmaf_rn(q.w, xv.w, d);
    }
    return __fmaf_rn(-2.f, d, __fadd_rn(xn, en));
}

__global__ void __launch_bounds__(TPB)
__attribute__((amdgpu_waves_per_eu(2, 2)))
vq_kernel(
        const float* __restrict__ x, const float* __restrict__ cb,
        float* __restrict__ out_q, float* __restrict__ out_idx) {
    __shared__ short xbf[BM * D_DIM];    // 32 KB bf16 x tile (swizzled rows)
    __shared__ short cbf[KTR * D_DIM];   // 32 KB bf16 cb tile (swizzled rows)
    __shared__ float es[K_CB];           // 4 KB
    __shared__ int   slots[BM * 8];      // 8 KB candidate slots
    __shared__ int   cnt[BM];            // 1 KB
    __shared__ int   bks[BM];            // 1 KB   total ~78 KB -> 2 blocks/CU

    const int tid = threadIdx.x;
    const int l   = tid & 63;
    const int w   = tid >> 6;
    const int lm  = l & 15;      // A-row / B-col / D-col lane component
    const int lg  = l >> 4;      // d-group / D-row-group component
    const size_t brow0 = (size_t)blockIdx.x * BM;
    const float4* cb4 = reinterpret_cast<const float4*>(cb);
    char* xb = reinterpret_cast<char*>(xbf);
    char* cc = reinterpret_cast<char*>(cbf);

    // ---- phase A: e-norms (numpy pairwise order, R4-verified) ----
#pragma unroll
    for (int j = 0; j < K_CB / TPB; ++j) {
        const int k = tid + TPB * j;
        const float4* cr = cb4 + (size_t)k * 16;
        float4 c0 = cr[0],  c1 = cr[1],  c2 = cr[2],  c3 = cr[3],
               c4 = cr[4],  c5 = cr[5],  c6 = cr[6],  c7 = cr[7],
               c8 = cr[8],  c9 = cr[9],  c10 = cr[10], c11 = cr[11],
               c12 = cr[12], c13 = cr[13], c14 = cr[14], c15 = cr[15];
        es[k] = np_pair_sq16(c0, c1, c2, c3, c4, c5, c6, c7,
                             c8, c9, c10, c11, c12, c13, c14, c15);
    }

    // ---- phase B: my row -> xn (fp32, numpy) + bf16 row into xbf ----
    float xn;
    {
        const float4* ga = reinterpret_cast<const float4*>(x + (brow0 + tid) * D_DIM);
        float4 v0 = ga[0],  v1 = ga[1],  v2 = ga[2],  v3 = ga[3],
               v4 = ga[4],  v5 = ga[5],  v6 = ga[6],  v7 = ga[7],
               v8 = ga[8],  v9 = ga[9],  v10 = ga[10], v11 = ga[11],
               v12 = ga[12], v13 = ga[13], v14 = ga[14], v15 = ga[15];
        xn = np_pair_sq16(v0, v1, v2, v3, v4, v5, v6, v7,
                          v8, v9, v10, v11, v12, v13, v14, v15);
        const int sw = (tid & 7) << 4;
#define XW(c, va, vb) { uint4 wv;                                           \
        wv.x = bf2(va.x, va.y); wv.y = bf2(va.z, va.w);                     \
        wv.z = bf2(vb.x, vb.y); wv.w = bf2(vb.z, vb.w);                     \
        *reinterpret_cast<uint4*>(xb + ((tid * 128 + (c) * 16) ^ sw)) = wv; }
        XW(0, v0,  v1)  XW(1, v2,  v3)  XW(2, v4,  v5)  XW(3, v6,  v7)
        XW(4, v8,  v9)  XW(5, v10, v11) XW(6, v12, v13) XW(7, v14, v15)
#undef XW
    }

    float rmv[4][4];
#pragma unroll
    for (int i = 0; i < 4; ++i)
#pragma unroll
        for (int r = 0; r < 4; ++r) rmv[i][r] = FLT_MAX;

    // ---- pass 1: MFMA sweep, per-lane running min ----
    for (int kt = 0; kt < NKT; ++kt) {
        __syncthreads();                 // prev tile readers done (kt=0: es/xbf ready)
        {   // stage cb tile kt as swizzled bf16
            const float4* src = cb4 + (size_t)kt * KTR * 16;
#pragma unroll
            for (int j = 0; j < KTR * 16 / TPB; ++j) {      // 16
                const int f = tid + TPB * j;
                const int kr = f >> 4, c = f & 15;
                const float4 v = src[f];
                uint2 wv; wv.x = bf2(v.x, v.y); wv.y = bf2(v.z, v.w);
                *reinterpret_cast<uint2*>(cc + ((kr * 128 + c * 8) ^ ((kr & 7) << 4))) = wv;
            }
        }
        __syncthreads();
#pragma unroll
        for (int rtl = 0; rtl < 4; ++rtl) {
            const int rb = w * 64 + rtl * 16 + lm;          // A-frag row
            const int rsw = (rb & 7) << 4;
            const short8 a0 = *reinterpret_cast<const short8*>(
                xb + ((rb * 128 + lg * 16) ^ rsw));
            const short8 a1 = *reinterpret_cast<const short8*>(
                xb + ((rb * 128 + lg * 16 + 64) ^ rsw));
#pragma unroll
            for (int ks = 0; ks < 16; ++ks) {
                const int kb = ks * 16 + lm;                // B-frag k-row (tile-local)
                const int ksw = (kb & 7) << 4;
                const short8 b0 = *reinterpret_cast<const short8*>(
                    cc + ((kb * 128 + lg * 16) ^ ksw));
                const short8 b1 = *reinterpret_cast<const short8*>(
                    cc + ((kb * 128 + lg * 16 + 64) ^ ksw));
                f32x4 acc = {0.f, 0.f, 0.f, 0.f};
                acc = __builtin_amdgcn_mfma_f32_16x16x32_bf16(a0, b0, acc, 0, 0, 0);
                acc = __builtin_amdgcn_mfma_f32_16x16x32_bf16(a1, b1, acc, 0, 0, 0);
                const float en = es[kt * KTR + kb];         // my D-col's k
#pragma unroll
                for (int r = 0; r < 4; ++r)
                    rmv[rtl][r] = fminf(rmv[rtl][r], __fmaf_rn(-2.f, acc[r], en));
            }
        }
    }

    // ---- reduce per-row min across the 16 D-col lanes; add margin ----
#pragma unroll
    for (int rtl = 0; rtl < 4; ++rtl)
#pragma unroll
        for (int r = 0; r < 4; ++r) {
            float v = rmv[rtl][r];
            v = fminf(v, __shfl_xor(v, 1));
            v = fminf(v, __shfl_xor(v, 2));
            v = fminf(v, __shfl_xor(v, 4));
            v = fminf(v, __shfl_xor(v, 8));
            rmv[rtl][r] = v + MARGIN;     // now the per-row threshold
        }

    cnt[tid] = 0;

    // ---- pass 2: identical sweep; push candidates t < threshold ----
    for (int kt = 0; kt < NKT; ++kt) {
        __syncthreads();                 // pass1 readers / cnt zero visible
        {
            const float4* src = cb4 + (size_t)kt * KTR * 16;
#pragma unroll
            for (int j = 0; j < KTR * 16 / TPB; ++j) {
                const int f = tid + TPB * j;
                const int kr = f >> 4, c = f & 15;
                const float4 v = src[f];
                uint2 wv; wv.x = bf2(v.x, v.y); wv.y = bf2(v.z, v.w);
                *reinterpret_cast<uint2*>(cc + ((kr * 128 + c * 8) ^ ((kr & 7) << 4))) = wv;
            }
        }
        __syncthreads();
#pragma unroll
        for (int rtl = 0; rtl < 4; ++rtl) {
            const int rb = w * 64 + rtl * 16 + lm;
            const int rsw = (rb & 7) << 4;
            const short8 a0 = *reinterpret_cast<const short8*>(
                xb + ((rb * 128 + lg * 16) ^ rsw));
            const short8 a1 = *reinterpret_cast<const short8*>(
                xb + ((rb * 128 + lg * 16 + 64) ^ rsw));
#pragma unroll
            for (int ks = 0; ks < 16; ++ks) {
                const int kb = ks * 16 + lm;
                const int ksw = (kb & 7) << 4;
                const short8 b0 = *reinterpret_cast<const short8*>(
                    cc + ((kb * 128 + lg * 16) ^ ksw));
                const short8 b1 = *reinterpret_cast<const short8*>(
                    cc + ((kb * 128 + lg * 16 + 64) ^ ksw));
                f32x4 acc = {0.f, 0.f, 0.f, 0.f};
                acc = __builtin_amdgcn_mfma_f32_16x16x32_bf16(a0, b0, acc, 0, 0, 0);
                acc = __builtin_amdgcn_mfma_f32_16x16x32_bf16(a1, b1, acc, 0, 0, 0);
                const int k = kt * KTR + kb;
                const float en = es[k];
                const bool c0 = __fmaf_rn(-2.f, acc[0], en) < rmv[rtl][0];
                const bool c1 = __fmaf_rn(-2.f, acc[1], en) < rmv[rtl][1];
                const bool c2 = __fmaf_rn(-2.f, acc[2], en) < rmv[rtl][2];
                const bool c3 = __fmaf_rn(-2.f, acc[3], en) < rmv[rtl][3];
                if (__any((int)(c0 | c1 | c2 | c3))) {
                    const int rowb = w * 64 + rtl * 16 + lg * 4;   // D-row base
                    if (c0) { const int i0 = atomicAdd(&cnt[rowb + 0], 1);
                              if (i0 < 8) slots[(rowb + 0) * 8 + i0] = k; }
                    if (c1) { const int i1 = atomicAdd(&cnt[rowb + 1], 1);
                              if (i1 < 8) slots[(rowb + 1) * 8 + i1] = k; }
                    if (c2) { const int i2 = atomicAdd(&cnt[rowb + 2], 1);
                              if (i2 < 8) slots[(rowb + 2) * 8 + i2] = k; }
                    if (c3) { const int i3 = atomicAdd(&cnt[rowb + 3], 1);
                              if (i3 < 8) slots[(rowb + 3) * 8 + i3] = k; }
                }
            }
        }
    }
    __syncthreads();

    // ---- exact rescore (bit-exact chain, first-min over candidate set) ----
    {
        const float* xp = x + (brow0 + tid) * D_DIM;
        float bs = FLT_MAX;
        int bk = 0;
        const int c = cnt[tid];
        if (c > 8) {                     // slot overflow (P~1e-5/block): full scan
#pragma unroll 1
            for (int k = 0; k < K_CB; ++k) {
                const float s = exact_sc(xp, cb, k, xn, es[k]);
                if (s < bs) { bs = s; bk = k; }
            }
        } else {
#pragma unroll 1
            for (int j = 0; j < c; ++j) {
                const int k = slots[tid * 8 + j];
                const float s = exact_sc(xp, cb, k, xn, es[k]);
                if (s < bs || (s == bs && k < bk)) { bs = s; bk = k; }
            }
        }
        bks[tid] = bk;
        out_idx[brow0 + tid] = (float)bk;
    }
    __syncthreads();

    // ---- phase D: coalesced gather-write of x_quantized ----
    float4* oq = reinterpret_cast<float4*>(out_q + brow0 * D_DIM);
#pragma unroll
    for (int j = 0; j < 16; ++j) {
        const int f = tid + TPB * j;     // 0..4095
        const int r = f >> 4, c = f & 15;
        oq[f] = cb4[(size_t)bks[r] * 16 + c];
    }
}

extern "C" void kernel_launch(void* const* d_in, const int* in_sizes, int n_in,
                              void* d_out, int out_size, void* d_ws, size_t ws_size,
                              hipStream_t stream) {
    const float* x  = (const float*)d_in[0];
    const float* cb = (const float*)d_in[1];
    const int n_rows = in_sizes[0] / D_DIM;     // 262144

    float* out_q   = (float*)d_out;
    float* out_idx = out_q + (size_t)n_rows * D_DIM;

    vq_kernel<<<n_rows / BM, TPB, 0, stream>>>(x, cb, out_q, out_idx);
}